// Round 4
// baseline (489.567 us; speedup 1.0000x reference)
//
#include <hip/hip_runtime.h>

#define EMB 1024
#define HID 4096
#define NB 2
#define TT 4096
#define MROWS (NB*TT)   // 8192
#define N1 (2*HID)      // 8192
#define CHUNK 128       // = GEMM1 row tile
#define NCH 32          // chunks per batch (TT/CHUNK)

typedef short short8 __attribute__((ext_vector_type(8)));
typedef float v4f   __attribute__((ext_vector_type(4)));

__device__ __forceinline__ unsigned short f2bf(float f) {
  unsigned int u = __float_as_uint(f);
  u += 0x7FFFu + ((u >> 16) & 1u);
  return (unsigned short)(u >> 16);
}
__device__ __forceinline__ float bf2f(unsigned short s) {
  return __uint_as_float(((unsigned int)s) << 16);
}
__device__ __forceinline__ void g2l16(const void* g, void* l) {
  __builtin_amdgcn_global_load_lds(
      (const __attribute__((address_space(1))) void*)g,
      (__attribute__((address_space(3))) void*)l, 16, 0, 0);
}

__device__ __forceinline__ float block_reduce_sum(float v, float* sbuf) {
  #pragma unroll
  for (int off = 32; off; off >>= 1) v += __shfl_down(v, off, 64);
  int lane = threadIdx.x & 63, w = threadIdx.x >> 6;
  if (lane == 0) sbuf[w] = v;
  __syncthreads();
  return sbuf[0] + sbuf[1] + sbuf[2] + sbuf[3];
}

// ---------- merged weight convert: W1|W2 -> w12_bf, W3 -> w3_bf ----------
__global__ __launch_bounds__(256) void conv_all(const float* __restrict__ W1,
                                                const float* __restrict__ W2,
                                                const float* __restrict__ W3,
                                                unsigned short* __restrict__ o12,
                                                unsigned short* __restrict__ o3) {
  size_t i = ((size_t)blockIdx.x*256 + threadIdx.x)*4;
  const float* s; unsigned short* d;
  if (i < (size_t)HID*EMB)        { s = W1 + i;                      d = o12 + i; }
  else if (i < 2ull*HID*EMB)      { s = W2 + (i - (size_t)HID*EMB);  d = o12 + i; }
  else                            { s = W3 + (i - 2ull*HID*EMB);     d = o3 + (i - 2ull*HID*EMB); }
  float4 v = *(const float4*)s;
  ushort4 u; u.x=f2bf(v.x); u.y=f2bf(v.y); u.z=f2bf(v.z); u.w=f2bf(v.w);
  *(ushort4*)d = u;
}

// ---------- rmsnorm (fp32 in, bf16 out), row = EMB ----------
__global__ __launch_bounds__(256) void rmsnorm_x(const float* __restrict__ x,
                                                 unsigned short* __restrict__ r) {
  __shared__ float sbuf[4];
  int row = blockIdx.x;
  float4 v = *(const float4*)(x + (size_t)row*EMB + threadIdx.x*4);
  float ss = v.x*v.x + v.y*v.y + v.z*v.z + v.w*v.w;
  float tot = block_reduce_sum(ss, sbuf);
  float sc = rsqrtf(tot * (1.0f/EMB) + 1e-6f);
  ushort4 o; o.x=f2bf(v.x*sc); o.y=f2bf(v.y*sc); o.z=f2bf(v.z*sc); o.w=f2bf(v.w*sc);
  *(ushort4*)(r + (size_t)row*EMB + threadIdx.x*4) = o;
}

// ---------- row sum-of-squares -> rsqrt scale (bf16 in), row = HID ----------
__global__ __launch_bounds__(256) void rowssq(const unsigned short* __restrict__ y,
                                              float* __restrict__ sc) {
  __shared__ float sbuf[4];
  int row = blockIdx.x;
  const unsigned short* p = y + (size_t)row*HID + threadIdx.x*16;
  short8 v0 = *(const short8*)p;
  short8 v1 = *(const short8*)(p+8);
  float ss = 0.f;
  #pragma unroll
  for (int j=0;j<8;++j){ float a=bf2f((unsigned short)v0[j]), b=bf2f((unsigned short)v1[j]); ss += a*a + b*b; }
  float tot = block_reduce_sum(ss, sbuf);
  if (threadIdx.x == 0) sc[row] = rsqrtf(tot*(1.0f/HID) + 1e-6f);
}

// ---------- out = x (pre-init for GEMM2 atomic accumulate) ----------
__global__ __launch_bounds__(256) void init_out(const float* __restrict__ x,
                                                float* __restrict__ o) {
  size_t i = ((size_t)blockIdx.x*256 + threadIdx.x)*4;
  *(float4*)(o + i) = *(const float4*)(x + i);
}

// ---------- bf16 MFMA GEMM, C = A(MxK) * Bt(NxK)^T ----------
// MODE 0: Ch = (fp16) exp(acc); per-block column sums -> part[col*64 + blockIdx.y]
// MODE 1: atomicAdd(Cf, Sc[row]*acc)  (split-K over blockIdx.z, chunk KCH)
// 128x128 tile, BK=64, 256 thr (4 waves, 2x2 of 64x64), XOR-swizzled LDS.
template<int MODE>
__global__ __launch_bounds__(256, 2)
void gemm_bt(const unsigned short* __restrict__ A,
             const unsigned short* __restrict__ Bt,
             unsigned short* __restrict__ Ch,
             float* __restrict__ Cf,
             const float* __restrict__ Sc,
             float* __restrict__ part,
             int K, int KCH, int N) {
  __shared__ short lA[128*64];
  __shared__ short lB[128*64];
  __shared__ float cs[2][128];
  const int tid  = threadIdx.x;
  const int lane = tid & 63;
  const int wm   = (tid >> 6) >> 1, wn = (tid >> 6) & 1;
  const int rowBase = blockIdx.y * 128;
  const int colBase = blockIdx.x * 128;
  const int kStart  = blockIdx.z * KCH;

  v4f acc[4][4];
  #pragma unroll
  for (int i=0;i<4;++i)
    #pragma unroll
    for (int j=0;j<4;++j) acc[i][j] = (v4f){0.f,0.f,0.f,0.f};

  for (int k0 = kStart; k0 < kStart + KCH; k0 += 64) {
    #pragma unroll
    for (int j = 0; j < 4; ++j) {
      int s = j*256 + tid;
      int m = s >> 3;
      int c = (s & 7) ^ (m & 7);
      g2l16(A + (size_t)(rowBase + m)*K + k0 + c*8, &lA[s*8]);
    }
    #pragma unroll
    for (int j = 0; j < 4; ++j) {
      int s = j*256 + tid;
      int m = s >> 3;
      int c = (s & 7) ^ (m & 7);
      g2l16(Bt + (size_t)(colBase + m)*K + k0 + c*8, &lB[s*8]);
    }
    __syncthreads();
    #pragma unroll
    for (int s2 = 0; s2 < 2; ++s2) {
      const int quad = lane >> 4;
      const int cc = s2*4 + quad;
      short8 aF[4], bF[4];
      #pragma unroll
      for (int mt = 0; mt < 4; ++mt) {
        int ml = wm*64 + mt*16 + (lane & 15);
        aF[mt] = *(const short8*)&lA[(ml*8 + (cc ^ (ml & 7)))*8];
      }
      #pragma unroll
      for (int nt = 0; nt < 4; ++nt) {
        int nl = wn*64 + nt*16 + (lane & 15);
        bF[nt] = *(const short8*)&lB[(nl*8 + (cc ^ (nl & 7)))*8];
      }
      #pragma unroll
      for (int mt = 0; mt < 4; ++mt)
        #pragma unroll
        for (int nt = 0; nt < 4; ++nt)
          acc[mt][nt] = __builtin_amdgcn_mfma_f32_16x16x32_bf16(aF[mt], bF[nt], acc[mt][nt], 0, 0, 0);
    }
    __syncthreads();
  }

  const int quad = lane >> 4, c15 = lane & 15;
  float csum[4] = {0.f, 0.f, 0.f, 0.f};
  #pragma unroll
  for (int mt = 0; mt < 4; ++mt) {
    #pragma unroll
    for (int nt = 0; nt < 4; ++nt) {
      int col = colBase + wn*64 + nt*16 + c15;
      #pragma unroll
      for (int r = 0; r < 4; ++r) {
        int row = rowBase + wm*64 + mt*16 + quad*4 + r;
        size_t idx = (size_t)row*N + col;
        float v = acc[mt][nt][r];
        if (MODE == 0) {
          float e = __expf(v);
          _Float16 h = (_Float16)e;
          Ch[idx] = *(unsigned short*)&h;
          csum[nt] += e;
        } else {
          unsafeAtomicAdd(&Cf[idx], Sc[row]*v);
        }
      }
    }
  }
  if (MODE == 0) {
    #pragma unroll
    for (int nt = 0; nt < 4; ++nt) {
      float s = csum[nt];
      s += __shfl_xor(s, 16, 64);
      s += __shfl_xor(s, 32, 64);
      if (lane < 16) cs[wm][wn*64 + nt*16 + lane] = s;
    }
    __syncthreads();
    if (tid < 128)
      part[(size_t)(colBase + tid)*64 + blockIdx.y] = cs[0][tid] + cs[1][tid];
  }
}

// ---------- emit y = Sa*Sb/t^2 (bf16); prefix over raw chunk sums in-thread ----------
__global__ __launch_bounds__(256) void scan_emit(const unsigned short* __restrict__ ab,
                                                 const float* __restrict__ part,
                                                 unsigned short* __restrict__ y) {
  int h = blockIdx.x*256 + threadIdx.x;     // 0..4095
  int cy = blockIdx.y, bb = blockIdx.z;
  const float* pp = part + (size_t)h*64 + bb*NCH;
  const float* pq = part + (size_t)(HID + h)*64 + bb*NCH;
  float sa = 0.f, sb = 0.f;
  for (int c = 0; c < cy; ++c) { sa += pp[c]; sb += pq[c]; }
  const unsigned short* pa = ab + ((size_t)(bb*TT + cy*CHUNK))*N1 + h;
  const unsigned short* pb = pa + HID;
  unsigned short* py = y + ((size_t)(bb*TT + cy*CHUNK))*HID + h;
  int t0 = cy*CHUNK;
  #pragma unroll 4
  for (int i = 0; i < CHUNK; ++i) {
    unsigned short ua = pa[(size_t)i*N1];
    unsigned short ub = pb[(size_t)i*N1];
    sa += (float)(*(const _Float16*)&ua);
    sb += (float)(*(const _Float16*)&ub);
    float inv = 1.0f / (float)(t0 + i + 1);
    py[(size_t)i*HID] = f2bf(sa*sb*inv*inv);
  }
}

extern "C" void kernel_launch(void* const* d_in, const int* in_sizes, int n_in,
                              void* d_out, int out_size, void* d_ws, size_t ws_size,
                              hipStream_t stream) {
  const float* x  = (const float*)d_in[0];
  const float* W1 = (const float*)d_in[1];
  const float* W2 = (const float*)d_in[2];
  const float* W3 = (const float*)d_in[3];
  float* out = (float*)d_out;
  char* ws = (char*)d_ws;

  unsigned short* r_bf   = (unsigned short*)(ws);                 // 16 MB
  unsigned short* w12_bf = (unsigned short*)(ws + 16777216ull);   // 16 MB
  unsigned short* w3_bf  = (unsigned short*)(ws + 33554432ull);   // 8 MB
  unsigned short* ab_h   = (unsigned short*)(ws + 41943040ull);   // 128 MB fp16
  unsigned short* y_bf   = (unsigned short*)(ws + 176160768ull);  // 64 MB
  float*          sc     = (float*)(ws + 243269632ull);           // 32 KB
  // part (raw per-chunk column sums) lives in d_out; dead before init_out
  float*          part   = (float*)d_out;                         // 2 MB

  conv_all<<<12288, 256, 0, stream>>>(W1, W2, W3, w12_bf, w3_bf);
  rmsnorm_x<<<MROWS, 256, 0, stream>>>(x, r_bf);
  gemm_bt<0><<<dim3(64,64,1), 256, 0, stream>>>(r_bf, w12_bf, ab_h, nullptr, nullptr, part, EMB, EMB, N1);
  scan_emit<<<dim3(16,NCH,2), 256, 0, stream>>>(ab_h, part, y_bf);
  rowssq<<<MROWS, 256, 0, stream>>>(y_bf, sc);
  init_out<<<8192, 256, 0, stream>>>(x, out);
  gemm_bt<1><<<dim3(8,64,4), 256, 0, stream>>>(y_bf, w3_bf, nullptr, out, sc, nullptr, HID, 1024, EMB);
}

// Round 5
// 448.468 us; speedup vs baseline: 1.0916x; 1.0916x over previous
//
#include <hip/hip_runtime.h>

#define EMB 1024
#define HID 4096
#define NB 2
#define TT 4096
#define MROWS (NB*TT)   // 8192
#define N1 (2*HID)      // 8192
#define CHUNK 128       // = GEMM1 row tile
#define NCH 32          // chunks per batch (TT/CHUNK)

typedef short short8 __attribute__((ext_vector_type(8)));
typedef float v4f   __attribute__((ext_vector_type(4)));

__device__ __forceinline__ unsigned short f2bf(float f) {
  unsigned int u = __float_as_uint(f);
  u += 0x7FFFu + ((u >> 16) & 1u);
  return (unsigned short)(u >> 16);
}
__device__ __forceinline__ float bf2f(unsigned short s) {
  return __uint_as_float(((unsigned int)s) << 16);
}
__device__ __forceinline__ float h2f(unsigned short u) {
  return (float)(*(const _Float16*)&u);
}
__device__ __forceinline__ void g2l16(const void* g, void* l) {
  __builtin_amdgcn_global_load_lds(
      (const __attribute__((address_space(1))) void*)g,
      (__attribute__((address_space(3))) void*)l, 16, 0, 0);
}

__device__ __forceinline__ float block_reduce_sum(float v, float* sbuf) {
  #pragma unroll
  for (int off = 32; off; off >>= 1) v += __shfl_down(v, off, 64);
  int lane = threadIdx.x & 63, w = threadIdx.x >> 6;
  if (lane == 0) sbuf[w] = v;
  __syncthreads();
  return sbuf[0] + sbuf[1] + sbuf[2] + sbuf[3];
}

// ---------- merged weight convert: W1|W2 -> w12_bf, W3 -> w3_bf ----------
__global__ __launch_bounds__(256) void conv_all(const float* __restrict__ W1,
                                                const float* __restrict__ W2,
                                                const float* __restrict__ W3,
                                                unsigned short* __restrict__ o12,
                                                unsigned short* __restrict__ o3) {
  size_t i = ((size_t)blockIdx.x*256 + threadIdx.x)*4;
  const float* s; unsigned short* d;
  if (i < (size_t)HID*EMB)        { s = W1 + i;                      d = o12 + i; }
  else if (i < 2ull*HID*EMB)      { s = W2 + (i - (size_t)HID*EMB);  d = o12 + i; }
  else                            { s = W3 + (i - 2ull*HID*EMB);     d = o3 + (i - 2ull*HID*EMB); }
  float4 v = *(const float4*)s;
  ushort4 u; u.x=f2bf(v.x); u.y=f2bf(v.y); u.z=f2bf(v.z); u.w=f2bf(v.w);
  *(ushort4*)d = u;
}

// ---------- rmsnorm (fp32 in, bf16 out), row = EMB ----------
__global__ __launch_bounds__(256) void rmsnorm_x(const float* __restrict__ x,
                                                 unsigned short* __restrict__ r) {
  __shared__ float sbuf[4];
  int row = blockIdx.x;
  float4 v = *(const float4*)(x + (size_t)row*EMB + threadIdx.x*4);
  float ss = v.x*v.x + v.y*v.y + v.z*v.z + v.w*v.w;
  float tot = block_reduce_sum(ss, sbuf);
  float sc = rsqrtf(tot * (1.0f/EMB) + 1e-6f);
  ushort4 o; o.x=f2bf(v.x*sc); o.y=f2bf(v.y*sc); o.z=f2bf(v.z*sc); o.w=f2bf(v.w*sc);
  *(ushort4*)(r + (size_t)row*EMB + threadIdx.x*4) = o;
}

// ---------- row sum-of-squares -> rsqrt scale (bf16 in), row = HID ----------
__global__ __launch_bounds__(256) void rowssq(const unsigned short* __restrict__ y,
                                              float* __restrict__ sc) {
  __shared__ float sbuf[4];
  int row = blockIdx.x;
  const unsigned short* p = y + (size_t)row*HID + threadIdx.x*16;
  short8 v0 = *(const short8*)p;
  short8 v1 = *(const short8*)(p+8);
  float ss = 0.f;
  #pragma unroll
  for (int j=0;j<8;++j){ float a=bf2f((unsigned short)v0[j]), b=bf2f((unsigned short)v1[j]); ss += a*a + b*b; }
  float tot = block_reduce_sum(ss, sbuf);
  if (threadIdx.x == 0) sc[row] = rsqrtf(tot*(1.0f/HID) + 1e-6f);
}

// ---------- bf16 MFMA GEMM, C = A(MxK) * Bt(NxK)^T ----------
// MODE 0: Ch = (fp16) exp(acc); per-block column sums -> part[col*64 + blockIdx.y]
// MODE 1: Ph[z][row][col] = (fp16) Sc[row]*acc   (split-K partials, chunk KCH)
// 128x128 tile, BK=64, 256 thr (4 waves, 2x2 of 64x64), XOR-swizzled LDS.
template<int MODE>
__global__ __launch_bounds__(256, 2)
void gemm_bt(const unsigned short* __restrict__ A,
             const unsigned short* __restrict__ Bt,
             unsigned short* __restrict__ Ch,
             const float* __restrict__ Sc,
             float* __restrict__ part,
             int K, int KCH, int N) {
  __shared__ short lA[128*64];
  __shared__ short lB[128*64];
  __shared__ float cs[2][128];
  const int tid  = threadIdx.x;
  const int lane = tid & 63;
  const int wm   = (tid >> 6) >> 1, wn = (tid >> 6) & 1;
  const int rowBase = blockIdx.y * 128;
  const int colBase = blockIdx.x * 128;
  const int kStart  = blockIdx.z * KCH;

  v4f acc[4][4];
  #pragma unroll
  for (int i=0;i<4;++i)
    #pragma unroll
    for (int j=0;j<4;++j) acc[i][j] = (v4f){0.f,0.f,0.f,0.f};

  for (int k0 = kStart; k0 < kStart + KCH; k0 += 64) {
    #pragma unroll
    for (int j = 0; j < 4; ++j) {
      int s = j*256 + tid;
      int m = s >> 3;
      int c = (s & 7) ^ (m & 7);
      g2l16(A + (size_t)(rowBase + m)*K + k0 + c*8, &lA[s*8]);
    }
    #pragma unroll
    for (int j = 0; j < 4; ++j) {
      int s = j*256 + tid;
      int m = s >> 3;
      int c = (s & 7) ^ (m & 7);
      g2l16(Bt + (size_t)(colBase + m)*K + k0 + c*8, &lB[s*8]);
    }
    __syncthreads();
    #pragma unroll
    for (int s2 = 0; s2 < 2; ++s2) {
      const int quad = lane >> 4;
      const int cc = s2*4 + quad;
      short8 aF[4], bF[4];
      #pragma unroll
      for (int mt = 0; mt < 4; ++mt) {
        int ml = wm*64 + mt*16 + (lane & 15);
        aF[mt] = *(const short8*)&lA[(ml*8 + (cc ^ (ml & 7)))*8];
      }
      #pragma unroll
      for (int nt = 0; nt < 4; ++nt) {
        int nl = wn*64 + nt*16 + (lane & 15);
        bF[nt] = *(const short8*)&lB[(nl*8 + (cc ^ (nl & 7)))*8];
      }
      #pragma unroll
      for (int mt = 0; mt < 4; ++mt)
        #pragma unroll
        for (int nt = 0; nt < 4; ++nt)
          acc[mt][nt] = __builtin_amdgcn_mfma_f32_16x16x32_bf16(aF[mt], bF[nt], acc[mt][nt], 0, 0, 0);
    }
    __syncthreads();
  }

  const int quad = lane >> 4, c15 = lane & 15;
  float csum[4] = {0.f, 0.f, 0.f, 0.f};
  #pragma unroll
  for (int mt = 0; mt < 4; ++mt) {
    #pragma unroll
    for (int nt = 0; nt < 4; ++nt) {
      int col = colBase + wn*64 + nt*16 + c15;
      #pragma unroll
      for (int r = 0; r < 4; ++r) {
        int row = rowBase + wm*64 + mt*16 + quad*4 + r;
        float v = acc[mt][nt][r];
        if (MODE == 0) {
          size_t idx = (size_t)row*N + col;
          float e = __expf(v);
          _Float16 h = (_Float16)e;
          Ch[idx] = *(unsigned short*)&h;
          csum[nt] += e;
        } else {
          size_t idx = ((size_t)blockIdx.z*MROWS + row)*N + col;
          _Float16 h = (_Float16)(Sc[row]*v);
          Ch[idx] = *(unsigned short*)&h;
        }
      }
    }
  }
  if (MODE == 0) {
    #pragma unroll
    for (int nt = 0; nt < 4; ++nt) {
      float s = csum[nt];
      s += __shfl_xor(s, 16, 64);
      s += __shfl_xor(s, 32, 64);
      if (lane < 16) cs[wm][wn*64 + nt*16 + lane] = s;
    }
    __syncthreads();
    if (tid < 128)
      part[(size_t)(colBase + tid)*64 + blockIdx.y] = cs[0][tid] + cs[1][tid];
  }
}

// ---------- emit y = Sa*Sb/t^2 (bf16); prefix over raw chunk sums in-thread ----------
__global__ __launch_bounds__(256) void scan_emit(const unsigned short* __restrict__ ab,
                                                 const float* __restrict__ part,
                                                 unsigned short* __restrict__ y) {
  int h = blockIdx.x*256 + threadIdx.x;     // 0..4095
  int cy = blockIdx.y, bb = blockIdx.z;
  const float* pp = part + (size_t)h*64 + bb*NCH;
  const float* pq = part + (size_t)(HID + h)*64 + bb*NCH;
  float sa = 0.f, sb = 0.f;
  for (int c = 0; c < cy; ++c) { sa += pp[c]; sb += pq[c]; }
  const unsigned short* pa = ab + ((size_t)(bb*TT + cy*CHUNK))*N1 + h;
  const unsigned short* pb = pa + HID;
  unsigned short* py = y + ((size_t)(bb*TT + cy*CHUNK))*HID + h;
  int t0 = cy*CHUNK;
  #pragma unroll 4
  for (int i = 0; i < CHUNK; ++i) {
    sa += h2f(pa[(size_t)i*N1]);
    sb += h2f(pb[(size_t)i*N1]);
    float inv = 1.0f / (float)(t0 + i + 1);
    py[(size_t)i*HID] = f2bf(sa*sb*inv*inv);
  }
}

// ---------- out = x + sum_z partial_z (fp16 partials) ----------
__global__ __launch_bounds__(256) void reduce_out(const unsigned short* __restrict__ p,
                                                  const float* __restrict__ x,
                                                  float* __restrict__ o) {
  size_t i = ((size_t)blockIdx.x*256 + threadIdx.x)*4;
  float4 xv = *(const float4*)(x + i);
  float s0 = 0.f, s1 = 0.f, s2 = 0.f, s3 = 0.f;
  #pragma unroll
  for (int z = 0; z < 4; ++z) {
    ushort4 u = *(const ushort4*)(p + (size_t)z*MROWS*EMB + i);
    s0 += h2f(u.x); s1 += h2f(u.y); s2 += h2f(u.z); s3 += h2f(u.w);
  }
  float4 ov; ov.x = xv.x + s0; ov.y = xv.y + s1; ov.z = xv.z + s2; ov.w = xv.w + s3;
  *(float4*)(o + i) = ov;
}

extern "C" void kernel_launch(void* const* d_in, const int* in_sizes, int n_in,
                              void* d_out, int out_size, void* d_ws, size_t ws_size,
                              hipStream_t stream) {
  const float* x  = (const float*)d_in[0];
  const float* W1 = (const float*)d_in[1];
  const float* W2 = (const float*)d_in[2];
  const float* W3 = (const float*)d_in[3];
  float* out = (float*)d_out;
  char* ws = (char*)d_ws;

  unsigned short* r_bf   = (unsigned short*)(ws);                 // 16 MB
  unsigned short* w12_bf = (unsigned short*)(ws + 16777216ull);   // 16 MB
  unsigned short* w3_bf  = (unsigned short*)(ws + 33554432ull);   // 8 MB
  unsigned short* ab_h   = (unsigned short*)(ws + 41943040ull);   // 128 MB fp16
  unsigned short* y_bf   = (unsigned short*)(ws + 176160768ull);  // 64 MB
  float*          sc     = (float*)(ws + 243269632ull);           // 32 KB
  // psum (4 x 16 MB fp16 GEMM2 partials) reuses the dead ab region
  unsigned short* psum   = ab_h;
  // part (raw per-chunk column sums) lives in d_out; dead before reduce_out
  float*          part   = (float*)d_out;                         // 2 MB

  conv_all<<<12288, 256, 0, stream>>>(W1, W2, W3, w12_bf, w3_bf);
  rmsnorm_x<<<MROWS, 256, 0, stream>>>(x, r_bf);
  gemm_bt<0><<<dim3(64,64,1), 256, 0, stream>>>(r_bf, w12_bf, ab_h, nullptr, part, EMB, EMB, N1);
  scan_emit<<<dim3(16,NCH,2), 256, 0, stream>>>(ab_h, part, y_bf);
  rowssq<<<MROWS, 256, 0, stream>>>(y_bf, sc);
  gemm_bt<1><<<dim3(8,64,4), 256, 0, stream>>>(y_bf, w3_bf, psum, sc, nullptr, HID, 1024, EMB);
  reduce_out<<<8192, 256, 0, stream>>>(psum, x, out);
}

// Round 6
// 421.849 us; speedup vs baseline: 1.1605x; 1.0631x over previous
//
#include <hip/hip_runtime.h>

#define EMB 1024
#define HID 4096
#define NB 2
#define TT 4096
#define MROWS (NB*TT)   // 8192
#define N1 (2*HID)      // 8192
#define CHUNK 128       // = GEMM1 row tile
#define NCH 32          // chunks per batch (TT/CHUNK)

typedef short short8 __attribute__((ext_vector_type(8)));
typedef float v4f   __attribute__((ext_vector_type(4)));

__device__ __forceinline__ unsigned short f2bf(float f) {
  unsigned int u = __float_as_uint(f);
  u += 0x7FFFu + ((u >> 16) & 1u);
  return (unsigned short)(u >> 16);
}
__device__ __forceinline__ float bf2f(unsigned short s) {
  return __uint_as_float(((unsigned int)s) << 16);
}
__device__ __forceinline__ float h2f(unsigned short u) {
  return (float)(*(const _Float16*)&u);
}
__device__ __forceinline__ void g2l16(const void* g, void* l) {
  __builtin_amdgcn_global_load_lds(
      (const __attribute__((address_space(1))) void*)g,
      (__attribute__((address_space(3))) void*)l, 16, 0, 0);
}

__device__ __forceinline__ float block_reduce_sum(float v, float* sbuf) {
  #pragma unroll
  for (int off = 32; off; off >>= 1) v += __shfl_down(v, off, 64);
  int lane = threadIdx.x & 63, w = threadIdx.x >> 6;
  if (lane == 0) sbuf[w] = v;
  __syncthreads();
  return sbuf[0] + sbuf[1] + sbuf[2] + sbuf[3];
}

// ---------- merged weight convert: W1|W2 -> w12_bf, W3 -> w3_bf ----------
__global__ __launch_bounds__(256) void conv_all(const float* __restrict__ W1,
                                                const float* __restrict__ W2,
                                                const float* __restrict__ W3,
                                                unsigned short* __restrict__ o12,
                                                unsigned short* __restrict__ o3) {
  size_t i = ((size_t)blockIdx.x*256 + threadIdx.x)*4;
  const float* s; unsigned short* d;
  if (i < (size_t)HID*EMB)        { s = W1 + i;                      d = o12 + i; }
  else if (i < 2ull*HID*EMB)      { s = W2 + (i - (size_t)HID*EMB);  d = o12 + i; }
  else                            { s = W3 + (i - 2ull*HID*EMB);     d = o3 + (i - 2ull*HID*EMB); }
  float4 v = *(const float4*)s;
  ushort4 u; u.x=f2bf(v.x); u.y=f2bf(v.y); u.z=f2bf(v.z); u.w=f2bf(v.w);
  *(ushort4*)d = u;
}

// ---------- rmsnorm (fp32 in, bf16 out), row = EMB ----------
__global__ __launch_bounds__(256) void rmsnorm_x(const float* __restrict__ x,
                                                 unsigned short* __restrict__ r) {
  __shared__ float sbuf[4];
  int row = blockIdx.x;
  float4 v = *(const float4*)(x + (size_t)row*EMB + threadIdx.x*4);
  float ss = v.x*v.x + v.y*v.y + v.z*v.z + v.w*v.w;
  float tot = block_reduce_sum(ss, sbuf);
  float sc = rsqrtf(tot * (1.0f/EMB) + 1e-6f);
  ushort4 o; o.x=f2bf(v.x*sc); o.y=f2bf(v.y*sc); o.z=f2bf(v.z*sc); o.w=f2bf(v.w*sc);
  *(ushort4*)(r + (size_t)row*EMB + threadIdx.x*4) = o;
}

// ---------- row sum-of-squares -> rsqrt scale (bf16 in), row = HID ----------
__global__ __launch_bounds__(256) void rowssq(const unsigned short* __restrict__ y,
                                              float* __restrict__ sc) {
  __shared__ float sbuf[4];
  int row = blockIdx.x;
  const unsigned short* p = y + (size_t)row*HID + threadIdx.x*16;
  short8 v0 = *(const short8*)p;
  short8 v1 = *(const short8*)(p+8);
  float ss = 0.f;
  #pragma unroll
  for (int j=0;j<8;++j){ float a=bf2f((unsigned short)v0[j]), b=bf2f((unsigned short)v1[j]); ss += a*a + b*b; }
  float tot = block_reduce_sum(ss, sbuf);
  if (threadIdx.x == 0) sc[row] = rsqrtf(tot*(1.0f/HID) + 1e-6f);
}

// ---------- GEMM1: Ch = (fp16) exp(A*Bt^T); col-chunk sums -> part ----------
// 128x128 tile, BK=64, 256 thr (4 waves, 2x2 of 64x64), XOR-swizzled LDS.
// LDS exactly 32 KB (epilogue cs reuses lA) -> 5 blocks/CU.
__global__ __launch_bounds__(256, 2)
void gemm_exp(const unsigned short* __restrict__ A,
              const unsigned short* __restrict__ Bt,
              unsigned short* __restrict__ Ch,
              float* __restrict__ part,
              int K, int N) {
  __shared__ short lA[128*64];
  __shared__ short lB[128*64];
  const int tid  = threadIdx.x;
  const int lane = tid & 63;
  const int wm   = (tid >> 6) >> 1, wn = (tid >> 6) & 1;
  const int rowBase = blockIdx.y * 128;
  const int colBase = blockIdx.x * 128;

  v4f acc[4][4];
  #pragma unroll
  for (int i=0;i<4;++i)
    #pragma unroll
    for (int j=0;j<4;++j) acc[i][j] = (v4f){0.f,0.f,0.f,0.f};

  for (int k0 = 0; k0 < K; k0 += 64) {
    #pragma unroll
    for (int j = 0; j < 4; ++j) {
      int s = j*256 + tid;
      int m = s >> 3;
      int c = (s & 7) ^ (m & 7);
      g2l16(A + (size_t)(rowBase + m)*K + k0 + c*8, &lA[s*8]);
    }
    #pragma unroll
    for (int j = 0; j < 4; ++j) {
      int s = j*256 + tid;
      int m = s >> 3;
      int c = (s & 7) ^ (m & 7);
      g2l16(Bt + (size_t)(colBase + m)*K + k0 + c*8, &lB[s*8]);
    }
    __syncthreads();
    #pragma unroll
    for (int s2 = 0; s2 < 2; ++s2) {
      const int quad = lane >> 4;
      const int cc = s2*4 + quad;
      short8 aF[4], bF[4];
      #pragma unroll
      for (int mt = 0; mt < 4; ++mt) {
        int ml = wm*64 + mt*16 + (lane & 15);
        aF[mt] = *(const short8*)&lA[(ml*8 + (cc ^ (ml & 7)))*8];
      }
      #pragma unroll
      for (int nt = 0; nt < 4; ++nt) {
        int nl = wn*64 + nt*16 + (lane & 15);
        bF[nt] = *(const short8*)&lB[(nl*8 + (cc ^ (nl & 7)))*8];
      }
      #pragma unroll
      for (int mt = 0; mt < 4; ++mt)
        #pragma unroll
        for (int nt = 0; nt < 4; ++nt)
          acc[mt][nt] = __builtin_amdgcn_mfma_f32_16x16x32_bf16(aF[mt], bF[nt], acc[mt][nt], 0, 0, 0);
    }
    __syncthreads();
  }

  const int quad = lane >> 4, c15 = lane & 15;
  float csum[4] = {0.f, 0.f, 0.f, 0.f};
  #pragma unroll
  for (int mt = 0; mt < 4; ++mt) {
    #pragma unroll
    for (int nt = 0; nt < 4; ++nt) {
      int col = colBase + wn*64 + nt*16 + c15;
      #pragma unroll
      for (int r = 0; r < 4; ++r) {
        int row = rowBase + wm*64 + mt*16 + quad*4 + r;
        size_t idx = (size_t)row*N + col;
        float e = __expf(acc[mt][nt][r]);
        _Float16 h = (_Float16)e;
        Ch[idx] = *(unsigned short*)&h;
        csum[nt] += e;
      }
    }
  }
  // epilogue column sums; cs reuses lA (dead after final barrier above)
  float* cs = (float*)lA;   // [2][128]
  #pragma unroll
  for (int nt = 0; nt < 4; ++nt) {
    float s = csum[nt];
    s += __shfl_xor(s, 16, 64);
    s += __shfl_xor(s, 32, 64);
    if (lane < 16) cs[wm*128 + wn*64 + nt*16 + lane] = s;
  }
  __syncthreads();
  if (tid < 128)
    part[(size_t)(colBase + tid)*64 + blockIdx.y] = cs[tid] + cs[128 + tid];
}

// ---------- GEMM2: Ph[z][row][col] = (fp16) Sc[row]*(A*Bt^T), split-K ----------
__global__ __launch_bounds__(256, 2)
void gemm_out(const unsigned short* __restrict__ A,
              const unsigned short* __restrict__ Bt,
              unsigned short* __restrict__ Ph,
              const float* __restrict__ Sc,
              int K, int KCH, int N) {
  __shared__ short lA[128*64];
  __shared__ short lB[128*64];
  const int tid  = threadIdx.x;
  const int lane = tid & 63;
  const int wm   = (tid >> 6) >> 1, wn = (tid >> 6) & 1;
  const int rowBase = blockIdx.y * 128;
  const int colBase = blockIdx.x * 128;
  const int kStart  = blockIdx.z * KCH;

  v4f acc[4][4];
  #pragma unroll
  for (int i=0;i<4;++i)
    #pragma unroll
    for (int j=0;j<4;++j) acc[i][j] = (v4f){0.f,0.f,0.f,0.f};

  for (int k0 = kStart; k0 < kStart + KCH; k0 += 64) {
    #pragma unroll
    for (int j = 0; j < 4; ++j) {
      int s = j*256 + tid;
      int m = s >> 3;
      int c = (s & 7) ^ (m & 7);
      g2l16(A + (size_t)(rowBase + m)*K + k0 + c*8, &lA[s*8]);
    }
    #pragma unroll
    for (int j = 0; j < 4; ++j) {
      int s = j*256 + tid;
      int m = s >> 3;
      int c = (s & 7) ^ (m & 7);
      g2l16(Bt + (size_t)(colBase + m)*K + k0 + c*8, &lB[s*8]);
    }
    __syncthreads();
    #pragma unroll
    for (int s2 = 0; s2 < 2; ++s2) {
      const int quad = lane >> 4;
      const int cc = s2*4 + quad;
      short8 aF[4], bF[4];
      #pragma unroll
      for (int mt = 0; mt < 4; ++mt) {
        int ml = wm*64 + mt*16 + (lane & 15);
        aF[mt] = *(const short8*)&lA[(ml*8 + (cc ^ (ml & 7)))*8];
      }
      #pragma unroll
      for (int nt = 0; nt < 4; ++nt) {
        int nl = wn*64 + nt*16 + (lane & 15);
        bF[nt] = *(const short8*)&lB[(nl*8 + (cc ^ (nl & 7)))*8];
      }
      #pragma unroll
      for (int mt = 0; mt < 4; ++mt)
        #pragma unroll
        for (int nt = 0; nt < 4; ++nt)
          acc[mt][nt] = __builtin_amdgcn_mfma_f32_16x16x32_bf16(aF[mt], bF[nt], acc[mt][nt], 0, 0, 0);
    }
    __syncthreads();
  }

  const int quad = lane >> 4, c15 = lane & 15;
  #pragma unroll
  for (int mt = 0; mt < 4; ++mt) {
    #pragma unroll
    for (int nt = 0; nt < 4; ++nt) {
      int col = colBase + wn*64 + nt*16 + c15;
      #pragma unroll
      for (int r = 0; r < 4; ++r) {
        int row = rowBase + wm*64 + mt*16 + quad*4 + r;
        size_t idx = ((size_t)blockIdx.z*MROWS + row)*N + col;
        _Float16 h = (_Float16)(Sc[row]*acc[mt][nt][r]);
        Ph[idx] = *(unsigned short*)&h;
      }
    }
  }
}

// ---------- exclusive prefix over 32 chunks per (col, batch) ----------
__global__ __launch_bounds__(256) void scan_prefix(float* __restrict__ part) {
  int idx = blockIdx.x*256 + threadIdx.x;   // 0..16383
  int col = idx >> 1, bb = idx & 1;
  float* p = part + (size_t)col*64 + bb*NCH;
  float run = 0.f;
  #pragma unroll
  for (int c = 0; c < NCH; ++c) { float v = p[c]; p[c] = run; run += v; }
}

// ---------- emit y = Sa*Sb/t^2 (bf16), scanning fp16 exp values ----------
__global__ __launch_bounds__(256) void scan_emit(const unsigned short* __restrict__ ab,
                                                 const float* __restrict__ part,
                                                 unsigned short* __restrict__ y) {
  int h = blockIdx.x*256 + threadIdx.x;     // 0..4095
  int cy = blockIdx.y, bb = blockIdx.z;
  float sa = part[(size_t)h*64 + bb*NCH + cy];
  float sb = part[(size_t)(HID + h)*64 + bb*NCH + cy];
  const unsigned short* pa = ab + ((size_t)(bb*TT + cy*CHUNK))*N1 + h;
  const unsigned short* pb = pa + HID;
  unsigned short* py = y + ((size_t)(bb*TT + cy*CHUNK))*HID + h;
  int t0 = cy*CHUNK;
  #pragma unroll 4
  for (int i = 0; i < CHUNK; ++i) {
    sa += h2f(pa[(size_t)i*N1]);
    sb += h2f(pb[(size_t)i*N1]);
    float inv = 1.0f / (float)(t0 + i + 1);
    py[(size_t)i*HID] = f2bf(sa*sb*inv*inv);
  }
}

// ---------- out = x + sum_z partial_z (fp16 partials) ----------
__global__ __launch_bounds__(256) void reduce_out(const unsigned short* __restrict__ p,
                                                  const float* __restrict__ x,
                                                  float* __restrict__ o) {
  size_t i = ((size_t)blockIdx.x*256 + threadIdx.x)*4;
  float4 xv = *(const float4*)(x + i);
  float s0 = 0.f, s1 = 0.f, s2 = 0.f, s3 = 0.f;
  #pragma unroll
  for (int z = 0; z < 4; ++z) {
    ushort4 u = *(const ushort4*)(p + (size_t)z*MROWS*EMB + i);
    s0 += h2f(u.x); s1 += h2f(u.y); s2 += h2f(u.z); s3 += h2f(u.w);
  }
  float4 ov; ov.x = xv.x + s0; ov.y = xv.y + s1; ov.z = xv.z + s2; ov.w = xv.w + s3;
  *(float4*)(o + i) = ov;
}

extern "C" void kernel_launch(void* const* d_in, const int* in_sizes, int n_in,
                              void* d_out, int out_size, void* d_ws, size_t ws_size,
                              hipStream_t stream) {
  const float* x  = (const float*)d_in[0];
  const float* W1 = (const float*)d_in[1];
  const float* W2 = (const float*)d_in[2];
  const float* W3 = (const float*)d_in[3];
  float* out = (float*)d_out;
  char* ws = (char*)d_ws;

  unsigned short* r_bf   = (unsigned short*)(ws);                 // 16 MB
  unsigned short* w12_bf = (unsigned short*)(ws + 16777216ull);   // 16 MB
  unsigned short* w3_bf  = (unsigned short*)(ws + 33554432ull);   // 8 MB
  unsigned short* ab_h   = (unsigned short*)(ws + 41943040ull);   // 128 MB fp16
  unsigned short* y_bf   = (unsigned short*)(ws + 176160768ull);  // 64 MB
  float*          sc     = (float*)(ws + 243269632ull);           // 32 KB
  // psum (4 x 16 MB fp16 GEMM2 partials) reuses the dead ab region
  unsigned short* psum   = ab_h;
  // part (per-chunk column sums) lives in d_out; dead before reduce_out
  float*          part   = (float*)d_out;                         // 2 MB

  conv_all<<<12288, 256, 0, stream>>>(W1, W2, W3, w12_bf, w3_bf);
  rmsnorm_x<<<MROWS, 256, 0, stream>>>(x, r_bf);
  gemm_exp<<<dim3(64,64), 256, 0, stream>>>(r_bf, w12_bf, ab_h, part, EMB, N1);
  scan_prefix<<<64, 256, 0, stream>>>(part);
  scan_emit<<<dim3(16,NCH,2), 256, 0, stream>>>(ab_h, part, y_bf);
  rowssq<<<MROWS, 256, 0, stream>>>(y_bf, sc);
  gemm_out<<<dim3(8,64,4), 256, 0, stream>>>(y_bf, w3_bf, psum, sc, HID, 1024, EMB);
  reduce_out<<<8192, 256, 0, stream>>>(psum, x, out);
}